// Round 1
// baseline (150.132 us; speedup 1.0000x reference)
//
#include <hip/hip_runtime.h>

#define Bz 8
#define Lz 2048
#define Dz 256
#define Nz 64
#define SP 68   // b128-aligned LDS stride (power matmuls)
#define SA 65   // scalar-access LDS stride (conflict-free rows+cols)
#define SAK 72  // gemm5 bf16 LDS stride (ushorts): 64 k + 8 pad
#define SKB 136 // out7 bf16 LDS stride (ushorts)
#define KE 4    // Taylor order: ||64*dt*A|| <= ~0.15 -> rel err ~6e-7
#define KP 7    // p-chain depth = KE + 3 (dB phi1 terms)
#define BSP 4   // scan: blocks per channel (batch split)
#define BPB (Bz / BSP)   // 2 batches per block

typedef __attribute__((ext_vector_type(8))) short bf16x8;
typedef __attribute__((ext_vector_type(4))) float f32x4;

__device__ __forceinline__ float softplusf(float x) {
  return (x > 20.f) ? x : log1pf(expf(x));
}

__device__ __forceinline__ unsigned short f2bf(float f) {  // RNE fp32->bf16
  unsigned int u = __float_as_uint(f);
  u += 0x7fffu + ((u >> 16) & 1u);
  return (unsigned short)(u >> 16);
}

// acc = row n of (LA * LB), cols q*16..q*16+15 (SP strides). No barriers.
__device__ __forceinline__ void pmm_acc(const float* __restrict__ LA,
                                        const float* __restrict__ LB,
                                        float* acc, int n, int q) {
  float arow[64];
#pragma unroll
  for (int mm = 0; mm < 16; ++mm) {
    const float4 a4 = *(const float4*)(LA + n * SP + mm * 4);
    arow[4 * mm + 0] = a4.x; arow[4 * mm + 1] = a4.y;
    arow[4 * mm + 2] = a4.z; arow[4 * mm + 3] = a4.w;
  }
#pragma unroll
  for (int i = 0; i < 16; ++i) acc[i] = 0.f;
#pragma unroll 8
  for (int m = 0; m < 64; ++m) {
    const float4 b0 = *(const float4*)(LB + m * SP + q * 16 + 0);
    const float4 b1 = *(const float4*)(LB + m * SP + q * 16 + 4);
    const float4 b2 = *(const float4*)(LB + m * SP + q * 16 + 8);
    const float4 b3 = *(const float4*)(LB + m * SP + q * 16 + 12);
    const float a = arow[m];
    acc[0]  = fmaf(a, b0.x, acc[0]);  acc[1]  = fmaf(a, b0.y, acc[1]);
    acc[2]  = fmaf(a, b0.z, acc[2]);  acc[3]  = fmaf(a, b0.w, acc[3]);
    acc[4]  = fmaf(a, b1.x, acc[4]);  acc[5]  = fmaf(a, b1.y, acc[5]);
    acc[6]  = fmaf(a, b1.z, acc[6]);  acc[7]  = fmaf(a, b1.w, acc[7]);
    acc[8]  = fmaf(a, b2.x, acc[8]);  acc[9]  = fmaf(a, b2.y, acc[9]);
    acc[10] = fmaf(a, b2.z, acc[10]); acc[11] = fmaf(a, b2.w, acc[11]);
    acc[12] = fmaf(a, b3.x, acc[12]); acc[13] = fmaf(a, b3.y, acc[13]);
    acc[14] = fmaf(a, b3.z, acc[14]); acc[15] = fmaf(a, b3.w, acc[15]);
  }
}

// ---- Transpose x[b][t][d] -> xT[d][b][t] (float4 both sides);
//      folds powinit (Apow[0] = softplus(log_A)). ----
__global__ __launch_bounds__(256) void s4_xt(const float* __restrict__ x,
                                             float* __restrict__ xT,
                                             const float* __restrict__ log_A,
                                             float* __restrict__ Apow) {
  if (blockIdx.x == 0 && blockIdx.y == 0) {
    const int i = blockIdx.z * 512 + threadIdx.x;
    Apow[i] = softplusf(log_A[i]);
    Apow[i + 256] = softplusf(log_A[i + 256]);
  }
  __shared__ float tile[64][69];
  const int t0 = blockIdx.x * 64, d0 = blockIdx.y * 64, b = blockIdx.z;
  const int rr = threadIdx.x >> 4;
  const int c4 = (threadIdx.x & 15) * 4;
#pragma unroll
  for (int p = 0; p < 4; ++p) {
    const int row = p * 16 + rr;
    const float4 v = *(const float4*)(x + ((size_t)b * Lz + t0 + row) * Dz + d0 + c4);
    tile[row][c4 + 0] = v.x; tile[row][c4 + 1] = v.y;
    tile[row][c4 + 2] = v.z; tile[row][c4 + 3] = v.w;
  }
  __syncthreads();
#pragma unroll
  for (int p = 0; p < 4; ++p) {
    const int dd = p * 16 + rr;
    float4 o;
    o.x = tile[c4 + 0][dd]; o.y = tile[c4 + 1][dd];
    o.z = tile[c4 + 2][dd]; o.w = tile[c4 + 3][dd];
    *(float4*)(xT + ((size_t)(d0 + dd) * Bz + b) * Lz + t0 + c4) = o;
  }
}

// ---- fused build + power-basis: blocks 0..255 per-d chains; blocks
//      256..258 compute A2 / A3 / A4 ----
__global__ __launch_bounds__(256, 1) void s4_buildpow(
    float* __restrict__ Apow, const float* __restrict__ Bp,
    const float* __restrict__ Cp, const float* __restrict__ log_delta,
    float* __restrict__ Gk, float* __restrict__ Qk,
    float* __restrict__ kloc, float* __restrict__ dts) {
  __shared__ float As[Nz * SA];
  __shared__ float Pst[KP + 1][Nz];
  __shared__ float Qst[KE + 1][Nz];
  __shared__ float Pv[Nz], Qv[Nz], dBs[Nz];
  __shared__ float prA[4][Nz + 8], prB[4][Nz + 8];
  __shared__ float zp[KE + 1][17], zs[KE + 1];
  __shared__ alignas(16) float PA[Nz * SP];
  __shared__ alignas(16) float PB[Nz * SP];
  const int tid = threadIdx.x;
  const int d = blockIdx.x;
  const int n = tid & 63, qq = tid >> 6;

  if (d >= Dz) {
    const int role = d - Dz;   // 0 -> A2, 1 -> A3 = A*A2, 2 -> A4 = A2*A2
#pragma unroll
    for (int i = 0; i < 4; ++i) {
      const int e = (tid + 256 * i) * 4;
      const int r = e >> 6, c = e & 63;
      const float4 v = *(const float4*)(Apow + e);
      *(float4*)&PA[r * SP + c] = v;
      *(float4*)&PB[r * SP + c] = v;
    }
    __syncthreads();
    float acc[16];
    pmm_acc(PA, PB, acc, n, qq);
    if (role == 0) {
      float* O = Apow + (size_t)1 * 4096;
#pragma unroll
      for (int v = 0; v < 4; ++v) {
        float4 o;
        o.x = acc[4 * v]; o.y = acc[4 * v + 1];
        o.z = acc[4 * v + 2]; o.w = acc[4 * v + 3];
        *(float4*)(O + n * 64 + qq * 16 + 4 * v) = o;
      }
      return;
    }
    __syncthreads();
#pragma unroll
    for (int i = 0; i < 16; ++i) {
      PB[n * SP + qq * 16 + i] = acc[i];
      if (role == 2) PA[n * SP + qq * 16 + i] = acc[i];
    }
    __syncthreads();
    pmm_acc(PA, PB, acc, n, qq);
    float* O = Apow + (size_t)(role + 1) * 4096;
#pragma unroll
    for (int v = 0; v < 4; ++v) {
      float4 o;
      o.x = acc[4 * v]; o.y = acc[4 * v + 1];
      o.z = acc[4 * v + 2]; o.w = acc[4 * v + 3];
      *(float4*)(O + n * 64 + qq * 16 + 4 * v) = o;
    }
    return;
  }

  const float dt = softplusf(log_delta[d]) + 1e-6f;
#pragma unroll
  for (int i = 0; i < 4; ++i) {
    const int e = (tid + 256 * i) * 4;
    const int r = e >> 6, c = e & 63;
    const float4 v = *(const float4*)(Apow + e);
    As[r * SA + c] = v.x; As[r * SA + c + 1] = v.y;
    As[r * SA + c + 2] = v.z; As[r * SA + c + 3] = v.w;
  }
  if (tid < 64) {
    const float bv = Bp[d * Nz + tid], cv = Cp[d * Nz + tid];
    Pv[tid] = bv; Pst[0][tid] = bv;
    Qv[tid] = cv; Qst[0][tid] = cv;
  }
  __syncthreads();
#pragma unroll 1
  for (int k = 1; k <= KP; ++k) {
    float pp = 0.f, pq = 0.f;
#pragma unroll
    for (int mm = 0; mm < 16; ++mm) {
      const int m = qq * 16 + mm;
      pp += As[n * SA + m] * Pv[m];   // (A p)[n]
      pq += As[m * SA + n] * Qv[m];   // (A^T q)[n]
    }
    prA[qq][n] = pp; prB[qq][n] = pq;
    __syncthreads();
    if (tid < 64) {
      const float np = prA[0][tid] + prA[1][tid] + prA[2][tid] + prA[3][tid];
      Pv[tid] = np; Pst[k][tid] = np;
      if (k <= KE) {
        const float nq = prB[0][tid] + prB[1][tid] + prB[2][tid] + prB[3][tid];
        Qv[tid] = nq; Qst[k][tid] = nq;
      }
    }
    __syncthreads();
  }
  const float dtc0 = dt;
  const float dtc1 = dt * dt * 0.5f;
  const float dtc2 = dtc1 * dt * (1.f / 3.f);
  const float dtc3 = dtc2 * dt * 0.25f;
  if (tid < 64) {
    dBs[tid] = dtc0 * Pst[0][tid] + dtc1 * Pst[1][tid] +
               dtc2 * Pst[2][tid] + dtc3 * Pst[3][tid];
#pragma unroll
    for (int k = 0; k <= KE; ++k) {
      Gk[(size_t)d * ((KE + 1) * 64) + k * 64 + tid] =
          dtc0 * Pst[k][tid] + dtc1 * Pst[k + 1][tid] +
          dtc2 * Pst[k + 2][tid] + dtc3 * Pst[k + 3][tid];
      Qk[(size_t)d * ((KE + 1) * 64) + k * 64 + tid] = Qst[k][tid];
    }
  }
  __syncthreads();
  if (tid < (KE + 1) * 16) {
    const int k = tid >> 4, seg = tid & 15;
    float s = 0.f;
#pragma unroll
    for (int i = 0; i < 4; ++i) s += Qst[k][seg * 4 + i] * dBs[seg * 4 + i];
    zp[k][seg] = s;
  }
  __syncthreads();
  if (tid <= KE) {
    float s = 0.f;
#pragma unroll
    for (int seg = 0; seg < 16; ++seg) s += zp[tid][seg];
    zs[tid] = s;
  }
  __syncthreads();
  if (tid < 64) {
    const float rdt = (float)tid * dt;
    float c = 1.f, acc = zs[0];
#pragma unroll
    for (int k = 1; k <= KE; ++k) { c *= rdt / (float)k; acc += c * zs[k]; }
    kloc[d * 64 + tid] = acc;
  }
  if (tid == 0) dts[d] = dt;
}

// Chunked state scan v5: double-buffered Ss/Xs -> 2 barriers per chunk.
// Chain per chunk c (cur=c&1, nxt=cur^1): stage(cur) [same-thread reads
// only] -> B1 -> compute -> pr -> B2 -> reduce into Ss[nxt] (consumed
// same-thread by next stage; broadcast covered by next B1).
__global__ __launch_bounds__(256) void s4_scan5(
    const float* __restrict__ xT, const float* __restrict__ Apow,
    const float* __restrict__ Gk, const float* __restrict__ dts,
    float* __restrict__ S) {
  __shared__ float Es[Nz * SA];
  __shared__ float Gs[(KE + 1) * Nz];
  __shared__ float CTs[KE + 1][66];
  __shared__ alignas(16) float Xs[2][BPB][64];
  __shared__ alignas(16) float Ss[2][BPB][64];
  __shared__ float pr[4][BPB][64];
  const int d = blockIdx.x;
  const int z = blockIdx.y;
  const int tid = threadIdx.x, n = tid & 63, q = tid >> 6;
  const int rb = tid >> 6;               // staging/reduce ownership (rb < BPB)
  const float dt = dts[d];
  if (tid < 65) {
    const float rdt = (float)tid * dt;
    float c = 1.f;
    CTs[0][tid] = 1.f;
#pragma unroll
    for (int k = 1; k <= KE; ++k) { c *= rdt / (float)k; CTs[k][tid] = c; }
  }
  for (int idx = tid; idx < (KE + 1) * 64; idx += 256)
    Gs[idx] = Gk[(size_t)d * ((KE + 1) * 64) + idx];
  {
    float ea[16];
#pragma unroll
    for (int i = 0; i < 16; ++i) ea[i] = 0.f;
    const float dt64 = 64.f * dt;
    float ce = 1.f;
#pragma unroll 1
    for (int k = 1; k <= KE; ++k) {
      ce *= dt64 / (float)k;
      const float* Ak = Apow + (size_t)(k - 1) * 4096;
#pragma unroll
      for (int i = 0; i < 16; ++i)
        ea[i] = fmaf(ce, Ak[tid + 256 * i], ea[i]);
    }
#pragma unroll
    for (int i = 0; i < 16; ++i) {
      const int e = tid + 256 * i;
      const int r = e >> 6, c = e & 63;
      Es[r * SA + c] = ea[i] + ((r == c) ? 1.f : 0.f);
    }
  }
  __syncthreads();
  float Er[16], Ur[16];
#pragma unroll
  for (int i = 0; i < 16; ++i) Er[i] = Es[n * SA + q * 16 + i];
#pragma unroll
  for (int i = 0; i < 16; ++i) {
    const int j = q * 16 + i;
    float u = 0.f;
#pragma unroll
    for (int k = 0; k <= KE; ++k) u = fmaf(CTs[k][63 - j], Gs[k * 64 + n], u);
    Ur[i] = u;                    // = Uf[n][j] = (E^{63-j} dB)[n]
  }
  if (rb < BPB) Ss[0][rb][n] = 0.f;
  const float* xd = xT + ((size_t)d * Bz + z * BPB) * Lz;
  float* Sd = S + (size_t)d * (32 * 8 * 64) + (size_t)(z * BPB) * 64;
#pragma unroll 1
  for (int c = 0; c < 32; ++c) {
    const int cur = c & 1, nxt = cur ^ 1;
    if (rb < BPB) {
      Xs[cur][rb][n] = xd[(size_t)rb * Lz + c * 64 + n];
      Sd[c * 512 + rb * 64 + n] = Ss[cur][rb][n];   // same-thread value
    }
    __syncthreads();                            // B1: Xs/Ss[cur] visible
    float acc[BPB];
#pragma unroll
    for (int b = 0; b < BPB; ++b) {
      const float4 s0 = *(const float4*)&Ss[cur][b][q * 16 + 0];
      const float4 s1 = *(const float4*)&Ss[cur][b][q * 16 + 4];
      const float4 s2 = *(const float4*)&Ss[cur][b][q * 16 + 8];
      const float4 s3 = *(const float4*)&Ss[cur][b][q * 16 + 12];
      const float4 x0 = *(const float4*)&Xs[cur][b][q * 16 + 0];
      const float4 x1 = *(const float4*)&Xs[cur][b][q * 16 + 4];
      const float4 x2 = *(const float4*)&Xs[cur][b][q * 16 + 8];
      const float4 x3 = *(const float4*)&Xs[cur][b][q * 16 + 12];
      float a = 0.f;
      a = fmaf(Er[0], s0.x, a);  a = fmaf(Er[1], s0.y, a);
      a = fmaf(Er[2], s0.z, a);  a = fmaf(Er[3], s0.w, a);
      a = fmaf(Er[4], s1.x, a);  a = fmaf(Er[5], s1.y, a);
      a = fmaf(Er[6], s1.z, a);  a = fmaf(Er[7], s1.w, a);
      a = fmaf(Er[8], s2.x, a);  a = fmaf(Er[9], s2.y, a);
      a = fmaf(Er[10], s2.z, a); a = fmaf(Er[11], s2.w, a);
      a = fmaf(Er[12], s3.x, a); a = fmaf(Er[13], s3.y, a);
      a = fmaf(Er[14], s3.z, a); a = fmaf(Er[15], s3.w, a);
      a = fmaf(Ur[0], x0.x, a);  a = fmaf(Ur[1], x0.y, a);
      a = fmaf(Ur[2], x0.z, a);  a = fmaf(Ur[3], x0.w, a);
      a = fmaf(Ur[4], x1.x, a);  a = fmaf(Ur[5], x1.y, a);
      a = fmaf(Ur[6], x1.z, a);  a = fmaf(Ur[7], x1.w, a);
      a = fmaf(Ur[8], x2.x, a);  a = fmaf(Ur[9], x2.y, a);
      a = fmaf(Ur[10], x2.z, a); a = fmaf(Ur[11], x2.w, a);
      a = fmaf(Ur[12], x3.x, a); a = fmaf(Ur[13], x3.y, a);
      a = fmaf(Ur[14], x3.z, a); a = fmaf(Ur[15], x3.w, a);
      acc[b] = a;
    }
#pragma unroll
    for (int b = 0; b < BPB; ++b) pr[q][b][n] = acc[b];
    __syncthreads();                            // B2: pr visible
    if (rb < BPB)
      Ss[nxt][rb][n] = pr[0][rb][n] + pr[1][rb][n] + pr[2][rb][n] + pr[3][rb][n];
    // no third barrier: next B1 publishes Ss[nxt]; stage read is same-thread
  }
}

// Output GEMM v7 (MFMA bf16): per (d, ch) block computes
//   y(64 t x 64 col) = M(64 x 128) . Z^T,  Z[col][k] = [S ; x] in bf16.
// Skip term folded into the Toeplitz diagonal: kx[0] += skip_D[d].
__global__ __launch_bounds__(256, 4) void s4_out7(
    const float* __restrict__ xT, const float* __restrict__ S,
    const float* __restrict__ Qk, const float* __restrict__ kloc,
    const float* __restrict__ dts, const float* __restrict__ skip_D,
    unsigned short* __restrict__ yb) {
  __shared__ alignas(16) unsigned short Msb[64 * SKB];  // [r(t)][k] bf16
  __shared__ alignas(16) unsigned short Zsb[64 * SKB];  // [col][k] bf16
  __shared__ float Qs[(KE + 1) * Nz];
  __shared__ float CT[KE + 1][66];
  __shared__ unsigned short kxb[64];
  const int d = blockIdx.x;
  const int ch = blockIdx.y;
  const int tid = threadIdx.x;
  const int wave = tid >> 6, lane = tid & 63;
  const int quad = lane >> 4, lq = lane & 15;
  const float dt = dts[d];
  if (tid < 65) {
    const float rdt = (float)tid * dt;
    float c = 1.f;
    CT[0][tid] = 1.f;
#pragma unroll
    for (int k = 1; k <= KE; ++k) { c *= rdt / (float)k; CT[k][tid] = c; }
  }
  for (int idx = tid; idx < (KE + 1) * 64; idx += 256)
    Qs[idx] = Qk[(size_t)d * ((KE + 1) * 64) + idx];
  if (tid < 64)
    kxb[tid] = f2bf(kloc[d * 64 + tid] + ((tid == 0) ? skip_D[d] : 0.f));

  const float* xd = xT + (size_t)d * Bz * Lz;
  const float* Sd = S + (size_t)d * (32 * 8 * 64);
#pragma unroll
  for (int p = 0; p < 8; ++p) {
    const int u = tid + 256 * p;
    const int col = u >> 5;          // 0..63
    const int sub = u & 31;          // which ushort4 within the col's 128 k
    const int k0 = sub * 4;
    const int bb = col & 7, ccl = col >> 3;
    const int cc = ch * 8 + ccl;
    const float* src = (k0 < 64)
        ? (Sd + cc * 512 + bb * 64 + k0)
        : (xd + (size_t)bb * Lz + cc * 64 + (k0 - 64));
    const float4 v = *(const float4*)src;
    ushort4 o;
    o.x = f2bf(v.x); o.y = f2bf(v.y); o.z = f2bf(v.z); o.w = f2bf(v.w);
    *(ushort4*)&Zsb[col * SKB + k0] = o;
  }
  __syncthreads();   // CT/Qs/kxb ready

#pragma unroll
  for (int i = 0; i < 16; ++i) {
    const int e = tid + 256 * i;
    const int r = e >> 6, m = e & 63;
    float w = 0.f;
#pragma unroll
    for (int k = 0; k <= KE; ++k) w = fmaf(CT[k][r + 1], Qs[k * 64 + m], w);
    Msb[r * SKB + m] = f2bf(w);
  }
#pragma unroll
  for (int i = 0; i < 16; ++i) {
    const int e = tid + 256 * i;
    const int r = e >> 6, j = e & 63;
    Msb[r * SKB + 64 + j] = (j <= r) ? kxb[r - j] : (unsigned short)0;
  }
  __syncthreads();   // Msb + Zsb ready

  f32x4 acc[4];
#pragma unroll
  for (int ni = 0; ni < 4; ++ni)
#pragma unroll
    for (int i = 0; i < 4; ++i) acc[ni][i] = 0.f;
#pragma unroll
  for (int ks = 0; ks < 4; ++ks) {
    const bf16x8 af =
        *(const bf16x8*)&Msb[(wave * 16 + lq) * SKB + ks * 32 + quad * 8];
#pragma unroll
    for (int ni = 0; ni < 4; ++ni) {
      const bf16x8 bfr =
          *(const bf16x8*)&Zsb[(ni * 16 + lq) * SKB + ks * 32 + quad * 8];
      acc[ni] = __builtin_amdgcn_mfma_f32_16x16x32_bf16(af, bfr, acc[ni], 0, 0, 0);
    }
  }
#pragma unroll
  for (int ni = 0; ni < 4; ++ni) {
    const int col = ni * 16 + lq;
    const int bb = col & 7, ccl = col >> 3;
    const int cc = ch * 8 + ccl;
    ushort4 o;
    o.x = f2bf(acc[ni][0]); o.y = f2bf(acc[ni][1]);
    o.z = f2bf(acc[ni][2]); o.w = f2bf(acc[ni][3]);
    *(ushort4*)(yb + ((size_t)d * Bz + bb) * Lz + cc * 64 + wave * 16 + quad * 4) = o;
  }
}

// Final GEMM v5 (MFMA bf16, BK=64): halved barrier count vs v4.
// out[row][c] = sum_d yb[d][row] * Wo[c][d] + bo[c]
__global__ __launch_bounds__(256, 2) void s4_gemm5(
    const unsigned short* __restrict__ yb, const float* __restrict__ Wo,
    const float* __restrict__ bo, float* __restrict__ out) {
  __shared__ alignas(16) unsigned short LA[128 * SAK];  // [row(t)][k'(d) 0..63]
  __shared__ alignas(16) unsigned short LB[64 * SAK];   // [c][k'(d) 0..63]
  const int tid = threadIdx.x;
  const int wave = tid >> 6, lane = tid & 63;
  const int quad = lane >> 4, lq = lane & 15;
  const int r0 = blockIdx.x * 128;
  const int c0 = blockIdx.y * 64;
  const int brow = r0 >> 11, t0 = r0 & 2047;
  const int ad = tid & 63;          // A staging: d-offset 0..63
  const int atg = tid >> 6;         // A staging: t-group of 32 (0..3)
  const int bc = tid >> 2;          // B staging: c-offset 0..63
  const int bko = tid & 3;          // B staging: k-octet 0..3 (x2 halves)
  f32x4 acc[2][4];
#pragma unroll
  for (int mi = 0; mi < 2; ++mi)
#pragma unroll
    for (int ni = 0; ni < 4; ++ni)
#pragma unroll
      for (int i = 0; i < 4; ++i) acc[mi][ni][i] = 0.f;
#pragma unroll 1
  for (int ks = 0; ks < 4; ++ks) {
    const int k0 = ks * 64;
    {
      const unsigned short* src =
          yb + ((size_t)(k0 + ad) * Bz + brow) * Lz + t0 + atg * 32;
#pragma unroll
      for (int h = 0; h < 4; ++h) {
        const bf16x8 v = *(const bf16x8*)(src + h * 8);
#pragma unroll
        for (int j = 0; j < 8; ++j)
          LA[(atg * 32 + h * 8 + j) * SAK + ad] = (unsigned short)v[j];
      }
    }
#pragma unroll
    for (int half = 0; half < 2; ++half) {
      const int kk = half * 32 + bko * 8;
      const float* wsrc = Wo + (size_t)(c0 + bc) * Dz + k0 + kk;
      const float4 w0 = *(const float4*)(wsrc);
      const float4 w1 = *(const float4*)(wsrc + 4);
      bf16x8 wv;
      wv[0] = (short)f2bf(w0.x); wv[1] = (short)f2bf(w0.y);
      wv[2] = (short)f2bf(w0.z); wv[3] = (short)f2bf(w0.w);
      wv[4] = (short)f2bf(w1.x); wv[5] = (short)f2bf(w1.y);
      wv[6] = (short)f2bf(w1.z); wv[7] = (short)f2bf(w1.w);
      *(bf16x8*)&LB[bc * SAK + kk] = wv;
    }
    __syncthreads();
#pragma unroll
    for (int ksub = 0; ksub < 2; ++ksub) {
      bf16x8 af[2], bfr[4];
#pragma unroll
      for (int mi = 0; mi < 2; ++mi)
        af[mi] = *(const bf16x8*)
            &LA[(wave * 32 + mi * 16 + lq) * SAK + ksub * 32 + quad * 8];
#pragma unroll
      for (int ni = 0; ni < 4; ++ni)
        bfr[ni] = *(const bf16x8*)
            &LB[(ni * 16 + lq) * SAK + ksub * 32 + quad * 8];
#pragma unroll
      for (int mi = 0; mi < 2; ++mi)
#pragma unroll
        for (int ni = 0; ni < 4; ++ni)
          acc[mi][ni] = __builtin_amdgcn_mfma_f32_16x16x32_bf16(
              af[mi], bfr[ni], acc[mi][ni], 0, 0, 0);
    }
    __syncthreads();
  }
  float bb[4];
#pragma unroll
  for (int ni = 0; ni < 4; ++ni) bb[ni] = bo[c0 + ni * 16 + lq];
#pragma unroll
  for (int mi = 0; mi < 2; ++mi)
#pragma unroll
    for (int i = 0; i < 4; ++i) {
      const int row = r0 + wave * 32 + mi * 16 + quad * 4 + i;
#pragma unroll
      for (int ni = 0; ni < 4; ++ni)
        out[(size_t)row * Dz + c0 + ni * 16 + lq] = acc[mi][ni][i] + bb[ni];
    }
}

extern "C" void kernel_launch(void* const* d_in, const int* in_sizes, int n_in,
                              void* d_out, int out_size, void* d_ws, size_t ws_size,
                              hipStream_t stream) {
  const float* x         = (const float*)d_in[0];
  const float* log_A     = (const float*)d_in[1];
  const float* Bp        = (const float*)d_in[2];
  const float* Cp        = (const float*)d_in[3];
  const float* log_delta = (const float*)d_in[4];
  const float* skip_D    = (const float*)d_in[5];
  const float* W_out     = (const float*)d_in[6];
  const float* b_out     = (const float*)d_in[7];
  float* out = (float*)d_out;

  float* xT   = (float*)d_ws;
  float* ybf  = xT + (size_t)Dz * Bz * Lz;       // bf16 yb lives in this slot
  float* S    = ybf + (size_t)Dz * Bz * Lz;
  float* Apow = S + (size_t)Dz * (32 * 8 * 64);
  float* Gk   = Apow + (size_t)8 * 4096;
  float* Qk   = Gk + (size_t)Dz * (KE + 1) * 64;
  float* kloc = Qk + (size_t)Dz * (KE + 1) * 64;
  float* dts  = kloc + (size_t)Dz * 64;
  unsigned short* yb = (unsigned short*)ybf;

  hipLaunchKernelGGL(s4_xt, dim3(Lz / 64, Dz / 64, Bz), dim3(256), 0, stream,
                     x, xT, log_A, Apow);
  hipLaunchKernelGGL(s4_buildpow, dim3(Dz + 3), dim3(256), 0, stream,
                     Apow, Bp, Cp, log_delta, Gk, Qk, kloc, dts);
  hipLaunchKernelGGL(s4_scan5, dim3(Dz, BSP), dim3(256), 0, stream,
                     xT, Apow, Gk, dts, S);
  hipLaunchKernelGGL(s4_out7, dim3(Dz, 4), dim3(256), 0, stream,
                     xT, S, Qk, kloc, dts, skip_D, yb);
  hipLaunchKernelGGL(s4_gemm5, dim3((Bz * Lz) / 128, Dz / 64), dim3(256), 0, stream,
                     yb, W_out, b_out, out);
}

// Round 2
// 137.028 us; speedup vs baseline: 1.0956x; 1.0956x over previous
//
#include <hip/hip_runtime.h>

#define Bz 8
#define Lz 2048
#define Dz 256
#define Nz 64
#define SP 68   // b128-aligned LDS stride (power matmuls)
#define SA 65   // scalar-access LDS stride (conflict-free rows+cols)
#define SAK 72  // gemm5 bf16 LDS stride (ushorts): 64 k + 8 pad
#define SKB 136 // out7 bf16 LDS stride (ushorts)
#define SE 68   // scan7 row stride (floats): 68*4=272 B, 16B-aligned rows
#define KE 4    // Taylor order: ||64*dt*A|| <= ~0.15 -> rel err ~6e-7
#define KP 7    // p-chain depth = KE + 3 (dB phi1 terms)

typedef __attribute__((ext_vector_type(8))) short bf16x8;
typedef __attribute__((ext_vector_type(4))) float f32x4;

__device__ __forceinline__ float softplusf(float x) {
  return (x > 20.f) ? x : log1pf(expf(x));
}

__device__ __forceinline__ unsigned short f2bf(float f) {  // RNE fp32->bf16
  unsigned int u = __float_as_uint(f);
  u += 0x7fffu + ((u >> 16) & 1u);
  return (unsigned short)(u >> 16);
}

// acc = row n of (LA * LB), cols q*16..q*16+15 (SP strides). No barriers.
__device__ __forceinline__ void pmm_acc(const float* __restrict__ LA,
                                        const float* __restrict__ LB,
                                        float* acc, int n, int q) {
  float arow[64];
#pragma unroll
  for (int mm = 0; mm < 16; ++mm) {
    const float4 a4 = *(const float4*)(LA + n * SP + mm * 4);
    arow[4 * mm + 0] = a4.x; arow[4 * mm + 1] = a4.y;
    arow[4 * mm + 2] = a4.z; arow[4 * mm + 3] = a4.w;
  }
#pragma unroll
  for (int i = 0; i < 16; ++i) acc[i] = 0.f;
#pragma unroll 8
  for (int m = 0; m < 64; ++m) {
    const float4 b0 = *(const float4*)(LB + m * SP + q * 16 + 0);
    const float4 b1 = *(const float4*)(LB + m * SP + q * 16 + 4);
    const float4 b2 = *(const float4*)(LB + m * SP + q * 16 + 8);
    const float4 b3 = *(const float4*)(LB + m * SP + q * 16 + 12);
    const float a = arow[m];
    acc[0]  = fmaf(a, b0.x, acc[0]);  acc[1]  = fmaf(a, b0.y, acc[1]);
    acc[2]  = fmaf(a, b0.z, acc[2]);  acc[3]  = fmaf(a, b0.w, acc[3]);
    acc[4]  = fmaf(a, b1.x, acc[4]);  acc[5]  = fmaf(a, b1.y, acc[5]);
    acc[6]  = fmaf(a, b1.z, acc[6]);  acc[7]  = fmaf(a, b1.w, acc[7]);
    acc[8]  = fmaf(a, b2.x, acc[8]);  acc[9]  = fmaf(a, b2.y, acc[9]);
    acc[10] = fmaf(a, b2.z, acc[10]); acc[11] = fmaf(a, b2.w, acc[11]);
    acc[12] = fmaf(a, b3.x, acc[12]); acc[13] = fmaf(a, b3.y, acc[13]);
    acc[14] = fmaf(a, b3.z, acc[14]); acc[15] = fmaf(a, b3.w, acc[15]);
  }
}

// ---- Transpose x[b][t][d] -> xT[d][b][t] (float4 both sides);
//      folds powinit (Apow[0] = softplus(log_A)). ----
__global__ __launch_bounds__(256) void s4_xt(const float* __restrict__ x,
                                             float* __restrict__ xT,
                                             const float* __restrict__ log_A,
                                             float* __restrict__ Apow) {
  if (blockIdx.x == 0 && blockIdx.y == 0) {
    const int i = blockIdx.z * 512 + threadIdx.x;
    Apow[i] = softplusf(log_A[i]);
    Apow[i + 256] = softplusf(log_A[i + 256]);
  }
  __shared__ float tile[64][69];
  const int t0 = blockIdx.x * 64, d0 = blockIdx.y * 64, b = blockIdx.z;
  const int rr = threadIdx.x >> 4;
  const int c4 = (threadIdx.x & 15) * 4;
#pragma unroll
  for (int p = 0; p < 4; ++p) {
    const int row = p * 16 + rr;
    const float4 v = *(const float4*)(x + ((size_t)b * Lz + t0 + row) * Dz + d0 + c4);
    tile[row][c4 + 0] = v.x; tile[row][c4 + 1] = v.y;
    tile[row][c4 + 2] = v.z; tile[row][c4 + 3] = v.w;
  }
  __syncthreads();
#pragma unroll
  for (int p = 0; p < 4; ++p) {
    const int dd = p * 16 + rr;
    float4 o;
    o.x = tile[c4 + 0][dd]; o.y = tile[c4 + 1][dd];
    o.z = tile[c4 + 2][dd]; o.w = tile[c4 + 3][dd];
    *(float4*)(xT + ((size_t)(d0 + dd) * Bz + b) * Lz + t0 + c4) = o;
  }
}

// ---- fused build + power-basis: blocks 0..255 per-d chains; blocks
//      256..258 compute A2 / A3 / A4 ----
__global__ __launch_bounds__(256, 1) void s4_buildpow(
    float* __restrict__ Apow, const float* __restrict__ Bp,
    const float* __restrict__ Cp, const float* __restrict__ log_delta,
    float* __restrict__ Gk, float* __restrict__ Qk,
    float* __restrict__ kloc, float* __restrict__ dts) {
  __shared__ float As[Nz * SA];
  __shared__ float Pst[KP + 1][Nz];
  __shared__ float Qst[KE + 1][Nz];
  __shared__ float Pv[Nz], Qv[Nz], dBs[Nz];
  __shared__ float prA[4][Nz + 8], prB[4][Nz + 8];
  __shared__ float zp[KE + 1][17], zs[KE + 1];
  __shared__ alignas(16) float PA[Nz * SP];
  __shared__ alignas(16) float PB[Nz * SP];
  const int tid = threadIdx.x;
  const int d = blockIdx.x;
  const int n = tid & 63, qq = tid >> 6;

  if (d >= Dz) {
    const int role = d - Dz;   // 0 -> A2, 1 -> A3 = A*A2, 2 -> A4 = A2*A2
#pragma unroll
    for (int i = 0; i < 4; ++i) {
      const int e = (tid + 256 * i) * 4;
      const int r = e >> 6, c = e & 63;
      const float4 v = *(const float4*)(Apow + e);
      *(float4*)&PA[r * SP + c] = v;
      *(float4*)&PB[r * SP + c] = v;
    }
    __syncthreads();
    float acc[16];
    pmm_acc(PA, PB, acc, n, qq);
    if (role == 0) {
      float* O = Apow + (size_t)1 * 4096;
#pragma unroll
      for (int v = 0; v < 4; ++v) {
        float4 o;
        o.x = acc[4 * v]; o.y = acc[4 * v + 1];
        o.z = acc[4 * v + 2]; o.w = acc[4 * v + 3];
        *(float4*)(O + n * 64 + qq * 16 + 4 * v) = o;
      }
      return;
    }
    __syncthreads();
#pragma unroll
    for (int i = 0; i < 16; ++i) {
      PB[n * SP + qq * 16 + i] = acc[i];
      if (role == 2) PA[n * SP + qq * 16 + i] = acc[i];
    }
    __syncthreads();
    pmm_acc(PA, PB, acc, n, qq);
    float* O = Apow + (size_t)(role + 1) * 4096;
#pragma unroll
    for (int v = 0; v < 4; ++v) {
      float4 o;
      o.x = acc[4 * v]; o.y = acc[4 * v + 1];
      o.z = acc[4 * v + 2]; o.w = acc[4 * v + 3];
      *(float4*)(O + n * 64 + qq * 16 + 4 * v) = o;
    }
    return;
  }

  const float dt = softplusf(log_delta[d]) + 1e-6f;
#pragma unroll
  for (int i = 0; i < 4; ++i) {
    const int e = (tid + 256 * i) * 4;
    const int r = e >> 6, c = e & 63;
    const float4 v = *(const float4*)(Apow + e);
    As[r * SA + c] = v.x; As[r * SA + c + 1] = v.y;
    As[r * SA + c + 2] = v.z; As[r * SA + c + 3] = v.w;
  }
  if (tid < 64) {
    const float bv = Bp[d * Nz + tid], cv = Cp[d * Nz + tid];
    Pv[tid] = bv; Pst[0][tid] = bv;
    Qv[tid] = cv; Qst[0][tid] = cv;
  }
  __syncthreads();
#pragma unroll 1
  for (int k = 1; k <= KP; ++k) {
    float pp = 0.f, pq = 0.f;
#pragma unroll
    for (int mm = 0; mm < 16; ++mm) {
      const int m = qq * 16 + mm;
      pp += As[n * SA + m] * Pv[m];   // (A p)[n]
      pq += As[m * SA + n] * Qv[m];   // (A^T q)[n]
    }
    prA[qq][n] = pp; prB[qq][n] = pq;
    __syncthreads();
    if (tid < 64) {
      const float np = prA[0][tid] + prA[1][tid] + prA[2][tid] + prA[3][tid];
      Pv[tid] = np; Pst[k][tid] = np;
      if (k <= KE) {
        const float nq = prB[0][tid] + prB[1][tid] + prB[2][tid] + prB[3][tid];
        Qv[tid] = nq; Qst[k][tid] = nq;
      }
    }
    __syncthreads();
  }
  const float dtc0 = dt;
  const float dtc1 = dt * dt * 0.5f;
  const float dtc2 = dtc1 * dt * (1.f / 3.f);
  const float dtc3 = dtc2 * dt * 0.25f;
  if (tid < 64) {
    dBs[tid] = dtc0 * Pst[0][tid] + dtc1 * Pst[1][tid] +
               dtc2 * Pst[2][tid] + dtc3 * Pst[3][tid];
#pragma unroll
    for (int k = 0; k <= KE; ++k) {
      Gk[(size_t)d * ((KE + 1) * 64) + k * 64 + tid] =
          dtc0 * Pst[k][tid] + dtc1 * Pst[k + 1][tid] +
          dtc2 * Pst[k + 2][tid] + dtc3 * Pst[k + 3][tid];
      Qk[(size_t)d * ((KE + 1) * 64) + k * 64 + tid] = Qst[k][tid];
    }
  }
  __syncthreads();
  if (tid < (KE + 1) * 16) {
    const int k = tid >> 4, seg = tid & 15;
    float s = 0.f;
#pragma unroll
    for (int i = 0; i < 4; ++i) s += Qst[k][seg * 4 + i] * dBs[seg * 4 + i];
    zp[k][seg] = s;
  }
  __syncthreads();
  if (tid <= KE) {
    float s = 0.f;
#pragma unroll
    for (int seg = 0; seg < 16; ++seg) s += zp[tid][seg];
    zs[tid] = s;
  }
  __syncthreads();
  if (tid < 64) {
    const float rdt = (float)tid * dt;
    float c = 1.f, acc = zs[0];
#pragma unroll
    for (int k = 1; k <= KE; ++k) { c *= rdt / (float)k; acc += c * zs[k]; }
    kloc[d * 64 + tid] = acc;
  }
  if (tid == 0) dts[d] = dt;
}

// Wave-autonomous state scan v7: one block per d, 512 threads = 8 waves =
// 8 batches. E-row + U-row live in VGPRs (64+64 per lane); S per-lane in a
// register. Per chunk (NO barriers, wave-local lgkmcnt ordering only):
//   ds_write S/x -> 32 uniform ds_read_b128 broadcasts -> 128 fma ->
//   coalesced global S store; x prefetched two chunks ahead in registers.
__global__ __launch_bounds__(512, 2) void s4_scan7(
    const float* __restrict__ xT, const float* __restrict__ Apow,
    const float* __restrict__ Gk, const float* __restrict__ dts,
    float* __restrict__ S) {
  __shared__ alignas(16) float Es[Nz * SE];
  __shared__ alignas(16) float Us[Nz * SE];
  __shared__ float Gs[(KE + 1) * Nz];
  __shared__ float CTs[KE + 1][66];
  __shared__ alignas(16) float Sw[Bz][SE];
  __shared__ alignas(16) float Xw[Bz][SE];
  const int d = blockIdx.x;
  const int tid = threadIdx.x;
  const int w = tid >> 6;          // wave = batch
  const int n = tid & 63;          // state row (lane)
  const float dt = dts[d];
  if (tid < 65) {
    const float rdt = (float)tid * dt;
    float c = 1.f;
    CTs[0][tid] = 1.f;
#pragma unroll
    for (int k = 1; k <= KE; ++k) { c *= rdt / (float)k; CTs[k][tid] = c; }
  }
  for (int idx = tid; idx < (KE + 1) * 64; idx += 512)
    Gs[idx] = Gk[(size_t)d * ((KE + 1) * 64) + idx];
  {  // E = I + Taylor(64*dt*A) via power basis Apow[0..KE-1]
    float ea[8];
#pragma unroll
    for (int i = 0; i < 8; ++i) ea[i] = 0.f;
    const float dt64 = 64.f * dt;
    float ce = 1.f;
#pragma unroll
    for (int k = 1; k <= KE; ++k) {
      ce *= dt64 / (float)k;
      const float* Ak = Apow + (size_t)(k - 1) * 4096;
#pragma unroll
      for (int i = 0; i < 8; ++i)
        ea[i] = fmaf(ce, Ak[tid + 512 * i], ea[i]);
    }
#pragma unroll
    for (int i = 0; i < 8; ++i) {
      const int e = tid + 512 * i;
      const int r = e >> 6, c = e & 63;
      Es[r * SE + c] = ea[i] + ((r == c) ? 1.f : 0.f);
    }
  }
  __syncthreads();   // CTs, Gs, Es ready
  {  // U[r][j] = sum_k CTs[k][63-j] * Gs[k][r]; thread owns row r, 8 j's
    const int r = tid >> 3, j0 = (tid & 7) * 8;
    float g0 = Gs[0 * 64 + r], g1 = Gs[1 * 64 + r], g2 = Gs[2 * 64 + r];
    float g3 = Gs[3 * 64 + r], g4 = Gs[4 * 64 + r];
#pragma unroll
    for (int jj = 0; jj < 8; ++jj) {
      const int j = j0 + jj;
      float u = g0 * CTs[0][63 - j];
      u = fmaf(g1, CTs[1][63 - j], u);
      u = fmaf(g2, CTs[2][63 - j], u);
      u = fmaf(g3, CTs[3][63 - j], u);
      u = fmaf(g4, CTs[4][63 - j], u);
      Us[r * SE + j] = u;
    }
  }
  __syncthreads();   // Us ready
  float Erow[64], Urow[64];
#pragma unroll
  for (int mb = 0; mb < 16; ++mb) {
    const float4 e4 = *(const float4*)&Es[n * SE + 4 * mb];
    Erow[4 * mb + 0] = e4.x; Erow[4 * mb + 1] = e4.y;
    Erow[4 * mb + 2] = e4.z; Erow[4 * mb + 3] = e4.w;
    const float4 u4 = *(const float4*)&Us[n * SE + 4 * mb];
    Urow[4 * mb + 0] = u4.x; Urow[4 * mb + 1] = u4.y;
    Urow[4 * mb + 2] = u4.z; Urow[4 * mb + 3] = u4.w;
  }
  const float* xw = xT + ((size_t)d * Bz + w) * (size_t)Lz;
  float* Sd = S + (size_t)d * (32 * 8 * 64) + w * 64 + n;
  float s = 0.f;
  float xcur = xw[n];           // chunk 0
  float xnxt = xw[64 + n];      // chunk 1
#pragma unroll 1
  for (int c = 0; c < 32; ++c) {
    Sw[w][n] = s;               // same-wave publish (lgkmcnt orders reads)
    Xw[w][n] = xcur;
    Sd[(size_t)c * 512] = s;    // chunk-boundary state (pre-update)
    const int cl = (c + 2 < 32) ? (c + 2) : 31;
    const float xnew = xw[cl * 64 + n];   // prefetch 2 ahead
    float a0 = 0.f, a1 = 0.f, a2 = 0.f, a3 = 0.f;
#pragma unroll
    for (int mb = 0; mb < 16; ++mb) {
      const float4 sb = *(const float4*)&Sw[w][4 * mb];   // uniform bcast
      a0 = fmaf(Erow[4 * mb + 0], sb.x, a0);
      a1 = fmaf(Erow[4 * mb + 1], sb.y, a1);
      a2 = fmaf(Erow[4 * mb + 2], sb.z, a2);
      a3 = fmaf(Erow[4 * mb + 3], sb.w, a3);
    }
#pragma unroll
    for (int jb = 0; jb < 16; ++jb) {
      const float4 xb = *(const float4*)&Xw[w][4 * jb];   // uniform bcast
      a0 = fmaf(Urow[4 * jb + 0], xb.x, a0);
      a1 = fmaf(Urow[4 * jb + 1], xb.y, a1);
      a2 = fmaf(Urow[4 * jb + 2], xb.z, a2);
      a3 = fmaf(Urow[4 * jb + 3], xb.w, a3);
    }
    s = (a0 + a1) + (a2 + a3);
    xcur = xnxt; xnxt = xnew;
  }
}

// Output GEMM v7 (MFMA bf16): per (d, ch) block computes
//   y(64 t x 64 col) = M(64 x 128) . Z^T,  Z[col][k] = [S ; x] in bf16.
// Skip term folded into the Toeplitz diagonal: kx[0] += skip_D[d].
__global__ __launch_bounds__(256, 4) void s4_out7(
    const float* __restrict__ xT, const float* __restrict__ S,
    const float* __restrict__ Qk, const float* __restrict__ kloc,
    const float* __restrict__ dts, const float* __restrict__ skip_D,
    unsigned short* __restrict__ yb) {
  __shared__ alignas(16) unsigned short Msb[64 * SKB];  // [r(t)][k] bf16
  __shared__ alignas(16) unsigned short Zsb[64 * SKB];  // [col][k] bf16
  __shared__ float Qs[(KE + 1) * Nz];
  __shared__ float CT[KE + 1][66];
  __shared__ unsigned short kxb[64];
  const int d = blockIdx.x;
  const int ch = blockIdx.y;
  const int tid = threadIdx.x;
  const int wave = tid >> 6, lane = tid & 63;
  const int quad = lane >> 4, lq = lane & 15;
  const float dt = dts[d];
  if (tid < 65) {
    const float rdt = (float)tid * dt;
    float c = 1.f;
    CT[0][tid] = 1.f;
#pragma unroll
    for (int k = 1; k <= KE; ++k) { c *= rdt / (float)k; CT[k][tid] = c; }
  }
  for (int idx = tid; idx < (KE + 1) * 64; idx += 256)
    Qs[idx] = Qk[(size_t)d * ((KE + 1) * 64) + idx];
  if (tid < 64)
    kxb[tid] = f2bf(kloc[d * 64 + tid] + ((tid == 0) ? skip_D[d] : 0.f));

  const float* xd = xT + (size_t)d * Bz * Lz;
  const float* Sd = S + (size_t)d * (32 * 8 * 64);
#pragma unroll
  for (int p = 0; p < 8; ++p) {
    const int u = tid + 256 * p;
    const int col = u >> 5;          // 0..63
    const int sub = u & 31;          // which ushort4 within the col's 128 k
    const int k0 = sub * 4;
    const int bb = col & 7, ccl = col >> 3;
    const int cc = ch * 8 + ccl;
    const float* src = (k0 < 64)
        ? (Sd + cc * 512 + bb * 64 + k0)
        : (xd + (size_t)bb * Lz + cc * 64 + (k0 - 64));
    const float4 v = *(const float4*)src;
    ushort4 o;
    o.x = f2bf(v.x); o.y = f2bf(v.y); o.z = f2bf(v.z); o.w = f2bf(v.w);
    *(ushort4*)&Zsb[col * SKB + k0] = o;
  }
  __syncthreads();   // CT/Qs/kxb ready

#pragma unroll
  for (int i = 0; i < 16; ++i) {
    const int e = tid + 256 * i;
    const int r = e >> 6, m = e & 63;
    float w = 0.f;
#pragma unroll
    for (int k = 0; k <= KE; ++k) w = fmaf(CT[k][r + 1], Qs[k * 64 + m], w);
    Msb[r * SKB + m] = f2bf(w);
  }
#pragma unroll
  for (int i = 0; i < 16; ++i) {
    const int e = tid + 256 * i;
    const int r = e >> 6, j = e & 63;
    Msb[r * SKB + 64 + j] = (j <= r) ? kxb[r - j] : (unsigned short)0;
  }
  __syncthreads();   // Msb + Zsb ready

  f32x4 acc[4];
#pragma unroll
  for (int ni = 0; ni < 4; ++ni)
#pragma unroll
    for (int i = 0; i < 4; ++i) acc[ni][i] = 0.f;
#pragma unroll
  for (int ks = 0; ks < 4; ++ks) {
    const bf16x8 af =
        *(const bf16x8*)&Msb[(wave * 16 + lq) * SKB + ks * 32 + quad * 8];
#pragma unroll
    for (int ni = 0; ni < 4; ++ni) {
      const bf16x8 bfr =
          *(const bf16x8*)&Zsb[(ni * 16 + lq) * SKB + ks * 32 + quad * 8];
      acc[ni] = __builtin_amdgcn_mfma_f32_16x16x32_bf16(af, bfr, acc[ni], 0, 0, 0);
    }
  }
#pragma unroll
  for (int ni = 0; ni < 4; ++ni) {
    const int col = ni * 16 + lq;
    const int bb = col & 7, ccl = col >> 3;
    const int cc = ch * 8 + ccl;
    ushort4 o;
    o.x = f2bf(acc[ni][0]); o.y = f2bf(acc[ni][1]);
    o.z = f2bf(acc[ni][2]); o.w = f2bf(acc[ni][3]);
    *(ushort4*)(yb + ((size_t)d * Bz + bb) * Lz + cc * 64 + wave * 16 + quad * 4) = o;
  }
}

// Final GEMM v5 (MFMA bf16, BK=64): halved barrier count vs v4.
// out[row][c] = sum_d yb[d][row] * Wo[c][d] + bo[c]
__global__ __launch_bounds__(256, 2) void s4_gemm5(
    const unsigned short* __restrict__ yb, const float* __restrict__ Wo,
    const float* __restrict__ bo, float* __restrict__ out) {
  __shared__ alignas(16) unsigned short LA[128 * SAK];  // [row(t)][k'(d) 0..63]
  __shared__ alignas(16) unsigned short LB[64 * SAK];   // [c][k'(d) 0..63]
  const int tid = threadIdx.x;
  const int wave = tid >> 6, lane = tid & 63;
  const int quad = lane >> 4, lq = lane & 15;
  const int r0 = blockIdx.x * 128;
  const int c0 = blockIdx.y * 64;
  const int brow = r0 >> 11, t0 = r0 & 2047;
  const int ad = tid & 63;          // A staging: d-offset 0..63
  const int atg = tid >> 6;         // A staging: t-group of 32 (0..3)
  const int bc = tid >> 2;          // B staging: c-offset 0..63
  const int bko = tid & 3;          // B staging: k-octet 0..3 (x2 halves)
  f32x4 acc[2][4];
#pragma unroll
  for (int mi = 0; mi < 2; ++mi)
#pragma unroll
    for (int ni = 0; ni < 4; ++ni)
#pragma unroll
      for (int i = 0; i < 4; ++i) acc[mi][ni][i] = 0.f;
#pragma unroll 1
  for (int ks = 0; ks < 4; ++ks) {
    const int k0 = ks * 64;
    {
      const unsigned short* src =
          yb + ((size_t)(k0 + ad) * Bz + brow) * Lz + t0 + atg * 32;
#pragma unroll
      for (int h = 0; h < 4; ++h) {
        const bf16x8 v = *(const bf16x8*)(src + h * 8);
#pragma unroll
        for (int j = 0; j < 8; ++j)
          LA[(atg * 32 + h * 8 + j) * SAK + ad] = (unsigned short)v[j];
      }
    }
#pragma unroll
    for (int half = 0; half < 2; ++half) {
      const int kk = half * 32 + bko * 8;
      const float* wsrc = Wo + (size_t)(c0 + bc) * Dz + k0 + kk;
      const float4 w0 = *(const float4*)(wsrc);
      const float4 w1 = *(const float4*)(wsrc + 4);
      bf16x8 wv;
      wv[0] = (short)f2bf(w0.x); wv[1] = (short)f2bf(w0.y);
      wv[2] = (short)f2bf(w0.z); wv[3] = (short)f2bf(w0.w);
      wv[4] = (short)f2bf(w1.x); wv[5] = (short)f2bf(w1.y);
      wv[6] = (short)f2bf(w1.z); wv[7] = (short)f2bf(w1.w);
      *(bf16x8*)&LB[bc * SAK + kk] = wv;
    }
    __syncthreads();
#pragma unroll
    for (int ksub = 0; ksub < 2; ++ksub) {
      bf16x8 af[2], bfr[4];
#pragma unroll
      for (int mi = 0; mi < 2; ++mi)
        af[mi] = *(const bf16x8*)
            &LA[(wave * 32 + mi * 16 + lq) * SAK + ksub * 32 + quad * 8];
#pragma unroll
      for (int ni = 0; ni < 4; ++ni)
        bfr[ni] = *(const bf16x8*)
            &LB[(ni * 16 + lq) * SAK + ksub * 32 + quad * 8];
#pragma unroll
      for (int mi = 0; mi < 2; ++mi)
#pragma unroll
        for (int ni = 0; ni < 4; ++ni)
          acc[mi][ni] = __builtin_amdgcn_mfma_f32_16x16x32_bf16(
              af[mi], bfr[ni], acc[mi][ni], 0, 0, 0);
    }
    __syncthreads();
  }
  float bb[4];
#pragma unroll
  for (int ni = 0; ni < 4; ++ni) bb[ni] = bo[c0 + ni * 16 + lq];
#pragma unroll
  for (int mi = 0; mi < 2; ++mi)
#pragma unroll
    for (int i = 0; i < 4; ++i) {
      const int row = r0 + wave * 32 + mi * 16 + quad * 4 + i;
#pragma unroll
      for (int ni = 0; ni < 4; ++ni)
        out[(size_t)row * Dz + c0 + ni * 16 + lq] = acc[mi][ni][i] + bb[ni];
    }
}

extern "C" void kernel_launch(void* const* d_in, const int* in_sizes, int n_in,
                              void* d_out, int out_size, void* d_ws, size_t ws_size,
                              hipStream_t stream) {
  const float* x         = (const float*)d_in[0];
  const float* log_A     = (const float*)d_in[1];
  const float* Bp        = (const float*)d_in[2];
  const float* Cp        = (const float*)d_in[3];
  const float* log_delta = (const float*)d_in[4];
  const float* skip_D    = (const float*)d_in[5];
  const float* W_out     = (const float*)d_in[6];
  const float* b_out     = (const float*)d_in[7];
  float* out = (float*)d_out;

  float* xT   = (float*)d_ws;
  float* ybf  = xT + (size_t)Dz * Bz * Lz;       // bf16 yb lives in this slot
  float* S    = ybf + (size_t)Dz * Bz * Lz;
  float* Apow = S + (size_t)Dz * (32 * 8 * 64);
  float* Gk   = Apow + (size_t)8 * 4096;
  float* Qk   = Gk + (size_t)Dz * (KE + 1) * 64;
  float* kloc = Qk + (size_t)Dz * (KE + 1) * 64;
  float* dts  = kloc + (size_t)Dz * 64;
  unsigned short* yb = (unsigned short*)ybf;

  hipLaunchKernelGGL(s4_xt, dim3(Lz / 64, Dz / 64, Bz), dim3(256), 0, stream,
                     x, xT, log_A, Apow);
  hipLaunchKernelGGL(s4_buildpow, dim3(Dz + 3), dim3(256), 0, stream,
                     Apow, Bp, Cp, log_delta, Gk, Qk, kloc, dts);
  hipLaunchKernelGGL(s4_scan7, dim3(Dz), dim3(512), 0, stream,
                     xT, Apow, Gk, dts, S);
  hipLaunchKernelGGL(s4_out7, dim3(Dz, 4), dim3(256), 0, stream,
                     xT, S, Qk, kloc, dts, skip_D, yb);
  hipLaunchKernelGGL(s4_gemm5, dim3((Bz * Lz) / 128, Dz / 64), dim3(256), 0, stream,
                     yb, W_out, b_out, out);
}